// Round 17
// baseline (146.656 us; speedup 1.0000x reference)
//
#include <hip/hip_runtime.h>

typedef _Float16 half_t;
typedef __fp16   fp16x2 __attribute__((ext_vector_type(2)));
typedef _Float16 half4_t __attribute__((ext_vector_type(4)));
typedef _Float16 half8   __attribute__((ext_vector_type(8)));
typedef float    f32x4   __attribute__((ext_vector_type(4)));
typedef unsigned short u16x8 __attribute__((ext_vector_type(8)));

#define KP_S    0.057735026918962574f  // 0.1/sqrt(3)
#define INV_EXT 11.547005383792515f    // 1/(0.05*sqrt(3))
#define NTILE   2500                   // 40000 queries / 16 per tile
#define WT_BYTES (64 * 1792 * 2)       // 229376
#define XH_BYTES (40000 * 64 * 2)      // 5120000
#define G_BYTES  (40000 * 3584)        // 143360000 (1792 fp16 per query)
#define GROW     3584                  // G bytes per query row

// ---- fused-path constants (r11 fallback) ----
#define GPITCH  3616
#define NBLK_F  512

union H8 { half8 v; fp16x2 h2[4]; };
union H4 { half4_t v; fp16x2 h2[2]; };

// ============================== pre-pass kernels ==============================

// x (f32, [40000][64]) -> xh (fp16, same layout): 128 B/row = 1 cache line
__global__ void build_xh(const float* __restrict__ x, half_t* __restrict__ xh) {
    int t = blockIdx.x * 256 + threadIdx.x;       // 2500*256 = 640000 exact
    f32x4 v = *(const f32x4*)(x + t * 4);
    H4 h;
    h.h2[0] = __builtin_amdgcn_cvt_pkrtz(v.x, v.y);
    h.h2[1] = __builtin_amdgcn_cvt_pkrtz(v.z, v.w);
    *(half4_t*)(xh + t * 4) = h.v;
}

// SPLIT path WT: kappa-ordered K axis matching kernel A's coalesced G stores.
// kappa<1024: nt=k>>8, m=(k>>2)&63, r=k&3, g=m>>4, lr=m&15 -> l=4g+r, i=16nt+lr
// kappa>=1024: u=k-1024, nt=u/192, v=u%192, m=v>>2, r=v&3, g=m>>4, lr=m&15
//              -> l=16+4g+r (<=27), i=16nt+lr
// channel perm c = 4*(i&15)+(i>>4) (gather = one 8B fp16 load per lane per row).
__global__ void build_wt_split(const float* __restrict__ W, half_t* __restrict__ WT) {
    int t = blockIdx.x * 256 + threadIdx.x;       // 64*1792 = 114688 exact
    if (t >= 64 * 1792) return;
    int o = t / 1792, k = t - o * 1792;
    int l, i;
    if (k < 1024) {
        int nt = k >> 8, m = (k >> 2) & 63, r = k & 3;
        l = 4 * (m >> 4) + r;  i = 16 * nt + (m & 15);
    } else {
        int u = k - 1024;
        int nt = u / 192, v = u - nt * 192;
        int m = v >> 2, r = v & 3;
        l = 16 + 4 * (m >> 4) + r;  i = 16 * nt + (m & 15);
    }
    int c = 4 * (i & 15) + (i >> 4);
    WT[t] = (half_t)W[(l * 64 + c) * 64 + o];
}

// FUSED fallback WT (r11): k = i*28 + l, l==27 zero pad
__global__ void build_wt_fused(const float* __restrict__ W, half_t* __restrict__ WT) {
    int t = blockIdx.x * 256 + threadIdx.x;       // 64*1792 = 114688 exact
    if (t >= 64 * 1792) return;
    int o = t / 1792, k = t - o * 1792;
    int i = k / 28,   l = k - i * 28;
    int c = 4 * (i & 15) + (i >> 4);
    WT[t] = (l < 27) ? (half_t)W[(l * 64 + c) * 64 + o] : (half_t)0.f;
}

// ========================= SPLIT kernel A: stage-1 ===========================
// 2500 blocks x 512 thr; 16 queries/block; wave handles 2; G stores coalesced.
__global__ __launch_bounds__(512, 4) void kpconvA(
    const float* __restrict__ q_pts, const float* __restrict__ s_pts,
    const int*   __restrict__ inds,  const half_t* __restrict__ xh,
    half_t* __restrict__ G)
{
    __shared__ __align__(16) unsigned short idx_lds[16][32];
    __shared__ __align__(16) f32x4 nbr_lds[16][32];

    const int tid  = threadIdx.x;
    const int lane = tid & 63, wid = tid >> 6;
    const int lr   = lane & 15, g = lane >> 4;
    const int aq   = tid >> 5,  ah = tid & 31;
    const int base = blockIdx.x * 16;

    const float kx0 = (float)((lr / 3) % 3 - 1) * KP_S;
    const float ky0 = (float)( lr / 9      - 1) * KP_S;
    const float kz0 = (float)( lr % 3      - 1) * KP_S;
    const int   l1  = lr + 16;
    const float kx1 = (float)((l1 / 3) % 3 - 1) * KP_S;
    const float ky1 = (float)( l1 / 9      - 1) * KP_S;
    const float kz1 = (float)( l1 % 3      - 1) * KP_S;
    const float cbias = (l1 < 27) ? 1.f : -1.f;

    // phase A: 16q x 32h, 1:1 threads
    {
        int n   = base + aq;
        int idx = inds[n * 32 + ah];
        idx_lds[aq][ah] = (unsigned short)idx;
        f32x4 v;
        v.x = s_pts[idx * 3 + 0] - q_pts[n * 3 + 0];
        v.y = s_pts[idx * 3 + 1] - q_pts[n * 3 + 1];
        v.z = s_pts[idx * 3 + 2] - q_pts[n * 3 + 2];
        v.w = 0.f;
        nbr_lds[aq][ah] = v;
    }
    __syncthreads();

    // both queries' gathers issued up front (in flight under w-compute)
    half4_t xvA[8], xvB[8];
    {
        u16x8 idA = *(const u16x8*)&idx_lds[2 * wid][8 * g];
        u16x8 idB = *(const u16x8*)&idx_lds[2 * wid + 1][8 * g];
        #pragma unroll
        for (int j = 0; j < 8; ++j) {
            xvA[j] = *(const half4_t*)(xh + (int)idA[j] * 64 + 4 * lr);
            xvB[j] = *(const half4_t*)(xh + (int)idB[j] * 64 + 4 * lr);
        }
    }

    #pragma unroll
    for (int qq = 0; qq < 2; ++qq) {
        const int q = 2 * wid + qq;
        float w0v[8], w1v[8];
        #pragma unroll
        for (int j = 0; j < 8; ++j) {
            f32x4 nb = nbr_lds[q][8 * g + j];
            float dx = nb.x - kx0, dy = nb.y - ky0, dz = nb.z - kz0;
            w0v[j] = fmaxf(fmaf(__builtin_amdgcn_sqrtf(dx*dx + dy*dy + dz*dz), -INV_EXT, 1.f), 0.f);
            float ex = nb.x - kx1, ey = nb.y - ky1, ez = nb.z - kz1;
            w1v[j] = fmaxf(fmaf(__builtin_amdgcn_sqrtf(ex*ex + ey*ey + ez*ez), -INV_EXT, cbias), 0.f);
        }
        H8 A0, A1;
        #pragma unroll
        for (int p = 0; p < 4; ++p) {
            A0.h2[p] = __builtin_amdgcn_cvt_pkrtz(w0v[2*p], w0v[2*p+1]);
            A1.h2[p] = __builtin_amdgcn_cvt_pkrtz(w1v[2*p], w1v[2*p+1]);
        }
        char* gq = (char*)G + (size_t)(base + q) * GROW;
        #pragma unroll
        for (int nt = 0; nt < 4; ++nt) {
            half8 b;
            #pragma unroll
            for (int j = 0; j < 8; ++j) b[j] = (qq ? xvB : xvA)[j][nt];
            f32x4 z = {0.f, 0.f, 0.f, 0.f};
            f32x4 c0 = __builtin_amdgcn_mfma_f32_16x16x32_f16(A0.v, b, z, 0, 0, 0);
            f32x4 c1 = __builtin_amdgcn_mfma_f32_16x16x32_f16(A1.v, b, z, 0, 0, 0);
            H4 h0;
            h0.h2[0] = __builtin_amdgcn_cvt_pkrtz(c0[0], c0[1]);
            h0.h2[1] = __builtin_amdgcn_cvt_pkrtz(c0[2], c0[3]);
            *(half4_t*)(gq + nt * 512 + lane * 8) = h0.v;          // 512B coalesced
            if (g < 3) {
                H4 h1;
                h1.h2[0] = __builtin_amdgcn_cvt_pkrtz(c1[0], c1[1]);
                h1.h2[1] = __builtin_amdgcn_cvt_pkrtz(c1[2], c1[3]);
                *(half4_t*)(gq + 2048 + nt * 384 + lane * 8) = h1.v; // 384B coalesced
            }
        }
    }
}

// ========================= SPLIT kernel B: stage-2 ===========================
// 625 blocks x 256 thr; wave = 16-query M-group, full K, all 64 o.
// Zero LDS, zero barriers; fully unrolled K-loop -> constant load offsets.
__global__ __launch_bounds__(256, 4) void kpconvB(
    const half_t* __restrict__ G, const half_t* __restrict__ WT,
    float* __restrict__ out)
{
    const int tid  = threadIdx.x;
    const int lane = tid & 63, wid = tid >> 6;    // 4 waves
    const int lr   = lane & 15, g = lane >> 4;
    const int m0   = blockIdx.x * 64 + wid * 16;  // wave's first query row

    const char*  ga = (const char*)G + (size_t)(m0 + lr) * GROW + 16 * g;
    const half_t* w0 = WT + (lr     ) * 1792 + 8 * g;
    const half_t* w1 = WT + (lr + 16) * 1792 + 8 * g;
    const half_t* w2 = WT + (lr + 32) * 1792 + 8 * g;
    const half_t* w3 = WT + (lr + 48) * 1792 + 8 * g;

    f32x4 acc0 = {0.f,0.f,0.f,0.f}, acc1 = {0.f,0.f,0.f,0.f};
    f32x4 acc2 = {0.f,0.f,0.f,0.f}, acc3 = {0.f,0.f,0.f,0.f};

    #pragma unroll
    for (int s = 0; s < 56; ++s) {                // 56*32 = 1792 = K exact
        half8 a  = *(const half8*)(ga + 64 * s);  // offset fits 13-bit imm
        half8 b0 = *(const half8*)(w0 + 32 * s);
        half8 b1 = *(const half8*)(w1 + 32 * s);
        half8 b2 = *(const half8*)(w2 + 32 * s);
        half8 b3 = *(const half8*)(w3 + 32 * s);
        acc0 = __builtin_amdgcn_mfma_f32_16x16x32_f16(a, b0, acc0, 0, 0, 0);
        acc1 = __builtin_amdgcn_mfma_f32_16x16x32_f16(a, b1, acc1, 0, 0, 0);
        acc2 = __builtin_amdgcn_mfma_f32_16x16x32_f16(a, b2, acc2, 0, 0, 0);
        acc3 = __builtin_amdgcn_mfma_f32_16x16x32_f16(a, b3, acc3, 0, 0, 0);
    }

    #pragma unroll
    for (int r = 0; r < 4; ++r) {
        float* orow = out + (m0 + 4 * g + r) * 64 + lr;
        orow[ 0] = acc0[r];
        orow[16] = acc1[r];
        orow[32] = acc2[r];
        orow[48] = acc3[r];
    }
}

// ===================== FUSED fallback (r11, 93us proven) =====================

#define ISSUE_XV1(BUF, Q, XV) do {                                             \
    u16x8 id8 = *(const u16x8*)&idx_lds[BUF][Q][8 * g];                        \
    _Pragma("unroll")                                                          \
    for (int j = 0; j < 8; ++j) {                                              \
        if constexpr (XHALF) {                                                 \
            XV[j] = *(const half4_t*)(xh + (int)id8[j] * 64 + 4 * lr);         \
        } else {                                                               \
            f32x4 t4 = *(const f32x4*)(x + (int)id8[j] * 64 + 4 * lr);         \
            H4 hh;                                                             \
            hh.h2[0] = __builtin_amdgcn_cvt_pkrtz(t4.x, t4.y);                 \
            hh.h2[1] = __builtin_amdgcn_cvt_pkrtz(t4.z, t4.w);                 \
            XV[j] = hh.v;                                                      \
        }                                                                      \
    }                                                                          \
} while (0)

#define PACK_B(XV, BF) do {                                                    \
    _Pragma("unroll")                                                          \
    for (int nt = 0; nt < 4; ++nt) {                                           \
        half8 b;                                                               \
        _Pragma("unroll")                                                      \
        for (int j = 0; j < 8; ++j) b[j] = XV[j][nt];                          \
        BF[nt].v = b;                                                          \
    }                                                                          \
} while (0)

#define MFMA_DUMP(Q, CUR, BF) do {                                             \
    float w0v[8], w1v[8];                                                      \
    _Pragma("unroll")                                                          \
    for (int j = 0; j < 8; ++j) {                                              \
        f32x4 nb = nbr_lds[CUR][Q][8 * g + j];                                 \
        float dx = nb.x - kx0, dy = nb.y - ky0, dz = nb.z - kz0;               \
        w0v[j] = fmaxf(fmaf(__builtin_amdgcn_sqrtf(dx*dx + dy*dy + dz*dz), -INV_EXT, 1.f), 0.f); \
        float ex = nb.x - kx1, ey = nb.y - ky1, ez = nb.z - kz1;               \
        w1v[j] = fmaxf(fmaf(__builtin_amdgcn_sqrtf(ex*ex + ey*ey + ez*ez), -INV_EXT, cbias), 0.f); \
    }                                                                          \
    H8 A0, A1;                                                                 \
    _Pragma("unroll")                                                          \
    for (int p = 0; p < 4; ++p) {                                              \
        A0.h2[p] = __builtin_amdgcn_cvt_pkrtz(w0v[2*p], w0v[2*p+1]);           \
        A1.h2[p] = __builtin_amdgcn_cvt_pkrtz(w1v[2*p], w1v[2*p+1]);           \
    }                                                                          \
    char* gq = g_mem + (Q) * GPITCH;                                           \
    _Pragma("unroll")                                                          \
    for (int nt = 0; nt < 4; ++nt) {                                           \
        f32x4 z = {0.f, 0.f, 0.f, 0.f};                                        \
        f32x4 c0 = __builtin_amdgcn_mfma_f32_16x16x32_f16(A0.v, BF[nt].v, z, 0, 0, 0); \
        f32x4 c1 = __builtin_amdgcn_mfma_f32_16x16x32_f16(A1.v, BF[nt].v, z, 0, 0, 0); \
        const int ic = 16 * nt + lr;                                           \
        H4 h0;                                                                 \
        h0.h2[0] = __builtin_amdgcn_cvt_pkrtz(c0[0], c0[1]);                   \
        h0.h2[1] = __builtin_amdgcn_cvt_pkrtz(c0[2], c0[3]);                   \
        *(half4_t*)(gq + 2 * (ic * 28 + 4 * g)) = h0.v;                        \
        if (4 * g < 12) {                                                      \
            H4 h1;                                                             \
            h1.h2[0] = __builtin_amdgcn_cvt_pkrtz(c1[0], c1[1]);               \
            h1.h2[1] = __builtin_amdgcn_cvt_pkrtz(c1[2], c1[3]);               \
            *(half4_t*)(gq + 2 * (ic * 28 + 16 + 4 * g)) = h1.v;               \
        }                                                                      \
    }                                                                          \
} while (0)

#define BODY(T, TN, CUR, XV) do {                                              \
    half4_t xvB[8];                                                            \
    ISSUE_XV1(CUR, 2 * wid + 1, xvB);                                          \
    H8 BFA[4];                                                                 \
    PACK_B(XV, BFA);                                                           \
    const int nn   = (TN) * 16 + aq;                                           \
    const int idxN = inds[nn * 32 + ah];                                       \
    MFMA_DUMP(2 * wid, CUR, BFA);                                              \
    f32x4 vN;                                                                  \
    vN.x = s_pts[idxN * 3 + 0] - q_pts[nn * 3 + 0];                            \
    vN.y = s_pts[idxN * 3 + 1] - q_pts[nn * 3 + 1];                            \
    vN.z = s_pts[idxN * 3 + 2] - q_pts[nn * 3 + 2];                            \
    vN.w = 0.f;                                                                \
    H8 BFB[4];                                                                 \
    PACK_B(xvB, BFB);                                                          \
    MFMA_DUMP(2 * wid + 1, CUR, BFB);                                          \
    idx_lds[(CUR) ^ 1][aq][ah] = (unsigned short)idxN;                         \
    nbr_lds[(CUR) ^ 1][aq][ah] = vN;                                           \
    __syncthreads();                                                           \
    ISSUE_XV1((CUR) ^ 1, 2 * wid, XV);                                         \
    const half_t* wrow = WT + (16 * ot + lr) * 1792 + kh * 896 + 8 * g;        \
    const char*   gb   = g_mem + lr * GPITCH + kh * 1792;                      \
    f32x4 accA = {0.f, 0.f, 0.f, 0.f}, accB = {0.f, 0.f, 0.f, 0.f};            \
    _Pragma("unroll 7")                                                        \
    for (int s = 0; s < 28; s += 2) {                                          \
        half8 aA = *(const half8*)(gb + 64 * s + 16 * g);                      \
        half8 bA = *(const half8*)(wrow + 32 * s);                             \
        accA = __builtin_amdgcn_mfma_f32_16x16x32_f16(aA, bA, accA, 0, 0, 0);  \
        half8 aB = *(const half8*)(gb + 64 * (s + 1) + 16 * g);                \
        half8 bB = *(const half8*)(wrow + 32 * (s + 1));                       \
        accB = __builtin_amdgcn_mfma_f32_16x16x32_f16(aB, bB, accB, 0, 0, 0);  \
    }                                                                          \
    f32x4 acc = accA + accB;                                                   \
    if (kh) *(f32x4*)&red[ot][lane] = acc;                                     \
    __syncthreads();                                                           \
    if (!kh) {                                                                 \
        f32x4 p = red[ot][lane];                                               \
        const int o = 16 * ot + lr;                                            \
        _Pragma("unroll")                                                      \
        for (int r = 0; r < 4; ++r)                                            \
            out[((T) * 16 + 4 * g + r) * 64 + o] = acc[r] + p[r];              \
    }                                                                          \
} while (0)

template <int XHALF>
__global__ __launch_bounds__(512, 4) void kpconv_fused(
    const float* __restrict__ q_pts, const float* __restrict__ s_pts,
    const int*   __restrict__ inds,  const float* __restrict__ x,
    const half_t* __restrict__ xh,   const half_t* __restrict__ WT,
    float* __restrict__ out)
{
    __shared__ __align__(16) char   g_mem[16 * GPITCH];
    __shared__ __align__(16) unsigned short idx_lds[2][16][32];
    __shared__ __align__(16) f32x4  nbr_lds[2][16][32];
    __shared__ __align__(16) f32x4  red[4][64];

    const int tid  = threadIdx.x;
    const int lane = tid & 63, wid = tid >> 6;
    const int lr   = lane & 15, g = lane >> 4;
    const int aq   = tid >> 5,  ah = tid & 31;
    const int ot   = wid & 3,   kh = wid >> 2;

    const float kx0 = (float)((lr / 3) % 3 - 1) * KP_S;
    const float ky0 = (float)( lr / 9      - 1) * KP_S;
    const float kz0 = (float)( lr % 3      - 1) * KP_S;
    const int   l1  = lr + 16;
    const float kx1 = (float)((l1 / 3) % 3 - 1) * KP_S;
    const float ky1 = (float)( l1 / 9      - 1) * KP_S;
    const float kz1 = (float)( l1 % 3      - 1) * KP_S;
    const float cbias = (l1 < 27) ? 1.f : -1.f;

    {
        int n   = blockIdx.x * 16 + aq;
        int idx = inds[n * 32 + ah];
        idx_lds[0][aq][ah] = (unsigned short)idx;
        f32x4 v;
        v.x = s_pts[idx * 3 + 0] - q_pts[n * 3 + 0];
        v.y = s_pts[idx * 3 + 1] - q_pts[n * 3 + 1];
        v.z = s_pts[idx * 3 + 2] - q_pts[n * 3 + 2];
        v.w = 0.f;
        nbr_lds[0][aq][ah] = v;
    }
    __syncthreads();

    half4_t xv[8];
    ISSUE_XV1(0, 2 * wid, xv);

    int cur = 0;
    for (int t = blockIdx.x; t < NTILE; t += NBLK_F) {
        int tn = (t + NBLK_F < NTILE) ? t + NBLK_F : t;
        BODY(t, tn, cur, xv);
        cur ^= 1;
    }
}

// ================================ launcher ===================================

extern "C" void kernel_launch(void* const* d_in, const int* in_sizes, int n_in,
                              void* d_out, int out_size, void* d_ws, size_t ws_size,
                              hipStream_t stream) {
    const float* q_pts = (const float*)d_in[0];
    const float* s_pts = (const float*)d_in[1];
    const int*   inds  = (const int*)d_in[2];
    const float* x     = (const float*)d_in[3];
    const float* W     = (const float*)d_in[4];
    float* out = (float*)d_out;
    half_t* WT = (half_t*)d_ws;                               // 229376 B
    half_t* xh = (half_t*)((char*)d_ws + WT_BYTES);           // 5120000 B
    half_t* G  = (half_t*)((char*)d_ws + WT_BYTES + XH_BYTES);// 143360000 B

    const size_t need_split = (size_t)WT_BYTES + XH_BYTES + G_BYTES;
    const size_t need_xh    = (size_t)WT_BYTES + XH_BYTES;

    if (ws_size >= need_split) {
        build_wt_split<<<448, 256, 0, stream>>>(W, WT);
        build_xh<<<2500, 256, 0, stream>>>(x, xh);
        kpconvA<<<2500, 512, 0, stream>>>(q_pts, s_pts, inds, xh, G);
        kpconvB<<<625, 256, 0, stream>>>(G, WT, out);
    } else if (ws_size >= need_xh) {
        build_wt_fused<<<448, 256, 0, stream>>>(W, WT);
        build_xh<<<2500, 256, 0, stream>>>(x, xh);
        kpconv_fused<1><<<NBLK_F, 512, 0, stream>>>(q_pts, s_pts, inds, x, xh, WT, out);
    } else {
        build_wt_fused<<<448, 256, 0, stream>>>(W, WT);
        kpconv_fused<0><<<NBLK_F, 512, 0, stream>>>(q_pts, s_pts, inds, x, xh, WT, out);
    }
}

// Round 18
// 86.678 us; speedup vs baseline: 1.6920x; 1.6920x over previous
//
#include <hip/hip_runtime.h>

typedef _Float16 half_t;
typedef __fp16   fp16x2 __attribute__((ext_vector_type(2)));
typedef _Float16 half4_t __attribute__((ext_vector_type(4)));
typedef _Float16 half8   __attribute__((ext_vector_type(8)));
typedef float    f32x4   __attribute__((ext_vector_type(4)));
typedef unsigned short u16x8 __attribute__((ext_vector_type(8)));

#define KP_S    0.057735026918962574f  // 0.1/sqrt(3)
#define INV_EXT 11.547005383792515f    // 1/(0.05*sqrt(3))
#define NTILE   2500                   // 40000 queries / 16 per tile
#define WT_BYTES (64 * 1792 * 2)       // 229376
#define XH_BYTES (40000 * 64 * 2)      // 5120000
#define G_BYTES  (40000 * 3584)        // 143360000
#define TROW     57344                 // G bytes per 16-query tile (56 s-blocks x 1024B)

// ---- fused-path constants (r11 fallback) ----
#define GPITCH  3616
#define NBLK_F  512

union H8 { half8 v; fp16x2 h2[4]; };
union H4 { half4_t v; fp16x2 h2[2]; };

// ============================== pre-pass kernels ==============================

// x (f32, [40000][64]) -> xh (fp16, same layout): 128 B/row = 1 cache line
__global__ void build_xh(const float* __restrict__ x, half_t* __restrict__ xh) {
    int t = blockIdx.x * 256 + threadIdx.x;       // 2500*256 = 640000 exact
    f32x4 v = *(const f32x4*)(x + t * 4);
    H4 h;
    h.h2[0] = __builtin_amdgcn_cvt_pkrtz(v.x, v.y);
    h.h2[1] = __builtin_amdgcn_cvt_pkrtz(v.z, v.w);
    *(half4_t*)(xh + t * 4) = h.v;
}

// SPLIT WT, TILED layout: element (o, kappa) stored at s*2048 + o*32 + r5
// (elements), s=kappa/32, r5=kappa%32. kappa->(l,i) map unchanged from r16:
// kappa<1024: nt=k>>8, m=(k>>2)&63, r=k&3 -> l=4*(m>>4)+r, i=16nt+(m&15)
// kappa>=1024: u=k-1024, nt=u/192, v=u%192, m=v>>2, r=v&3 -> l=16+4*(m>>4)+r
// channel perm c = 4*(i&15)+(i>>4).
__global__ void build_wt_split(const float* __restrict__ W, half_t* __restrict__ WT) {
    int t = blockIdx.x * 256 + threadIdx.x;       // 64*1792 = 114688 exact
    if (t >= 64 * 1792) return;
    int o = t / 1792, k = t - o * 1792;
    int l, i;
    if (k < 1024) {
        int nt = k >> 8, m = (k >> 2) & 63, r = k & 3;
        l = 4 * (m >> 4) + r;  i = 16 * nt + (m & 15);
    } else {
        int u = k - 1024;
        int nt = u / 192, v = u - nt * 192;
        int m = v >> 2, r = v & 3;
        l = 16 + 4 * (m >> 4) + r;  i = 16 * nt + (m & 15);
    }
    int c = 4 * (i & 15) + (i >> 4);
    WT[(k >> 5) * 2048 + o * 32 + (k & 31)] = (half_t)W[(l * 64 + c) * 64 + o];
}

// FUSED fallback WT (r11): k = i*28 + l, l==27 zero pad
__global__ void build_wt_fused(const float* __restrict__ W, half_t* __restrict__ WT) {
    int t = blockIdx.x * 256 + threadIdx.x;       // 64*1792 = 114688 exact
    if (t >= 64 * 1792) return;
    int o = t / 1792, k = t - o * 1792;
    int i = k / 28,   l = k - i * 28;
    int c = 4 * (i & 15) + (i >> 4);
    WT[t] = (l < 27) ? (half_t)W[(l * 64 + c) * 64 + o] : (half_t)0.f;
}

// ========================= SPLIT kernel A: stage-1 ===========================
// 2500 blocks x 512 thr; block = one 16-query tile; wave handles 2 queries.
// G stores use the TILED layout (8 x 64B runs per store instruction).
__global__ __launch_bounds__(512, 4) void kpconvA(
    const float* __restrict__ q_pts, const float* __restrict__ s_pts,
    const int*   __restrict__ inds,  const half_t* __restrict__ xh,
    half_t* __restrict__ G)
{
    __shared__ __align__(16) unsigned short idx_lds[16][32];
    __shared__ __align__(16) f32x4 nbr_lds[16][32];

    const int tid  = threadIdx.x;
    const int lane = tid & 63, wid = tid >> 6;
    const int lr   = lane & 15, g = lane >> 4;
    const int aq   = tid >> 5,  ah = tid & 31;
    const int base = blockIdx.x * 16;
    char* gt = (char*)G + (size_t)blockIdx.x * TROW;

    const float kx0 = (float)((lr / 3) % 3 - 1) * KP_S;
    const float ky0 = (float)( lr / 9      - 1) * KP_S;
    const float kz0 = (float)( lr % 3      - 1) * KP_S;
    const int   l1  = lr + 16;
    const float kx1 = (float)((l1 / 3) % 3 - 1) * KP_S;
    const float ky1 = (float)( l1 / 9      - 1) * KP_S;
    const float kz1 = (float)( l1 % 3      - 1) * KP_S;
    const float cbias = (l1 < 27) ? 1.f : -1.f;

    {
        int n   = base + aq;
        int idx = inds[n * 32 + ah];
        idx_lds[aq][ah] = (unsigned short)idx;
        f32x4 v;
        v.x = s_pts[idx * 3 + 0] - q_pts[n * 3 + 0];
        v.y = s_pts[idx * 3 + 1] - q_pts[n * 3 + 1];
        v.z = s_pts[idx * 3 + 2] - q_pts[n * 3 + 2];
        v.w = 0.f;
        nbr_lds[aq][ah] = v;
    }
    __syncthreads();

    half4_t xvA[8], xvB[8];
    {
        u16x8 idA = *(const u16x8*)&idx_lds[2 * wid][8 * g];
        u16x8 idB = *(const u16x8*)&idx_lds[2 * wid + 1][8 * g];
        #pragma unroll
        for (int j = 0; j < 8; ++j) {
            xvA[j] = *(const half4_t*)(xh + (int)idA[j] * 64 + 4 * lr);
            xvB[j] = *(const half4_t*)(xh + (int)idB[j] * 64 + 4 * lr);
        }
    }

    // tiled-store offsets (lane-invariant parts precomputed)
    const int so0 = (lane >> 3) * 1024 + (lane & 7) * 8;   // within c0 region
    #pragma unroll
    for (int qq = 0; qq < 2; ++qq) {
        const int q = 2 * wid + qq;
        float w0v[8], w1v[8];
        #pragma unroll
        for (int j = 0; j < 8; ++j) {
            f32x4 nb = nbr_lds[q][8 * g + j];
            float dx = nb.x - kx0, dy = nb.y - ky0, dz = nb.z - kz0;
            w0v[j] = fmaxf(fmaf(__builtin_amdgcn_sqrtf(dx*dx + dy*dy + dz*dz), -INV_EXT, 1.f), 0.f);
            float ex = nb.x - kx1, ey = nb.y - ky1, ez = nb.z - kz1;
            w1v[j] = fmaxf(fmaf(__builtin_amdgcn_sqrtf(ex*ex + ey*ey + ez*ez), -INV_EXT, cbias), 0.f);
        }
        H8 A0, A1;
        #pragma unroll
        for (int p = 0; p < 4; ++p) {
            A0.h2[p] = __builtin_amdgcn_cvt_pkrtz(w0v[2*p], w0v[2*p+1]);
            A1.h2[p] = __builtin_amdgcn_cvt_pkrtz(w1v[2*p], w1v[2*p+1]);
        }
        #pragma unroll
        for (int nt = 0; nt < 4; ++nt) {
            half8 b;
            #pragma unroll
            for (int j = 0; j < 8; ++j) b[j] = (qq ? xvB : xvA)[j][nt];
            f32x4 z = {0.f, 0.f, 0.f, 0.f};
            f32x4 c0 = __builtin_amdgcn_mfma_f32_16x16x32_f16(A0.v, b, z, 0, 0, 0);
            f32x4 c1 = __builtin_amdgcn_mfma_f32_16x16x32_f16(A1.v, b, z, 0, 0, 0);
            H4 h0;
            h0.h2[0] = __builtin_amdgcn_cvt_pkrtz(c0[0], c0[1]);
            h0.h2[1] = __builtin_amdgcn_cvt_pkrtz(c0[2], c0[3]);
            // kappa = nt*256 + lane*4 + r  ->  s = nt*8 + lane/8
            *(half4_t*)(gt + nt * 8192 + so0 + q * 64) = h0.v;
            if (lane < 48) {
                H4 h1;
                h1.h2[0] = __builtin_amdgcn_cvt_pkrtz(c1[0], c1[1]);
                h1.h2[1] = __builtin_amdgcn_cvt_pkrtz(c1[2], c1[3]);
                // kappa = 1024 + nt*192 + lane*4 + r -> s = 32 + nt*6 + lane/8
                *(half4_t*)(gt + 32768 + nt * 6144 + so0 + q * 64) = h1.v;
            }
        }
    }
}

// ========================= SPLIT kernel B: stage-2 ===========================
// 1250 blocks x 256 thr; 4 waves = K-quarters; each wave: 2 M-tiles (32 queries)
// sharing 4 WT streams. ALL loads 1KB-contiguous per wave (tiled layout).
__global__ __launch_bounds__(256, 4) void kpconvB(
    const half_t* __restrict__ G, const half_t* __restrict__ WT,
    float* __restrict__ out)
{
    __shared__ __align__(16) f32x4 red[3][2][4][64];   // 24576 B

    const int tid  = threadIdx.x;
    const int lane = tid & 63, kq = tid >> 6;
    const int lr   = lane & 15, g = lane >> 4;
    const int T0   = blockIdx.x * 2;

    const char* ga0 = (const char*)G + (size_t)T0 * TROW + kq * 14336 + lr * 64 + g * 16;
    const char* ga1 = ga0 + TROW;
    const char* wb  = (const char*)WT + kq * 57344 + lr * 64 + g * 16;

    f32x4 a00 = {0,0,0,0}, a01 = {0,0,0,0}, a02 = {0,0,0,0}, a03 = {0,0,0,0};
    f32x4 a10 = {0,0,0,0}, a11 = {0,0,0,0}, a12 = {0,0,0,0}, a13 = {0,0,0,0};

    #pragma unroll
    for (int s = 0; s < 14; ++s) {
        half8 av0 = *(const half8*)(ga0 + s * 1024);
        half8 av1 = *(const half8*)(ga1 + s * 1024);
        half8 b0  = *(const half8*)(wb + s * 4096);
        half8 b1  = *(const half8*)(wb + s * 4096 + 1024);
        half8 b2  = *(const half8*)(wb + s * 4096 + 2048);
        half8 b3  = *(const half8*)(wb + s * 4096 + 3072);
        a00 = __builtin_amdgcn_mfma_f32_16x16x32_f16(av0, b0, a00, 0, 0, 0);
        a01 = __builtin_amdgcn_mfma_f32_16x16x32_f16(av0, b1, a01, 0, 0, 0);
        a02 = __builtin_amdgcn_mfma_f32_16x16x32_f16(av0, b2, a02, 0, 0, 0);
        a03 = __builtin_amdgcn_mfma_f32_16x16x32_f16(av0, b3, a03, 0, 0, 0);
        a10 = __builtin_amdgcn_mfma_f32_16x16x32_f16(av1, b0, a10, 0, 0, 0);
        a11 = __builtin_amdgcn_mfma_f32_16x16x32_f16(av1, b1, a11, 0, 0, 0);
        a12 = __builtin_amdgcn_mfma_f32_16x16x32_f16(av1, b2, a12, 0, 0, 0);
        a13 = __builtin_amdgcn_mfma_f32_16x16x32_f16(av1, b3, a13, 0, 0, 0);
    }

    if (kq) {
        *(f32x4*)&red[kq - 1][0][0][lane] = a00;
        *(f32x4*)&red[kq - 1][0][1][lane] = a01;
        *(f32x4*)&red[kq - 1][0][2][lane] = a02;
        *(f32x4*)&red[kq - 1][0][3][lane] = a03;
        *(f32x4*)&red[kq - 1][1][0][lane] = a10;
        *(f32x4*)&red[kq - 1][1][1][lane] = a11;
        *(f32x4*)&red[kq - 1][1][2][lane] = a12;
        *(f32x4*)&red[kq - 1][1][3][lane] = a13;
    }
    __syncthreads();
    if (kq == 0) {
        f32x4 r0[4] = {a00, a01, a02, a03};
        f32x4 r1[4] = {a10, a11, a12, a13};
        #pragma unroll
        for (int j = 0; j < 4; ++j) {
            #pragma unroll
            for (int p = 0; p < 3; ++p) {
                r0[j] += red[p][0][j][lane];
                r1[j] += red[p][1][j][lane];
            }
        }
        #pragma unroll
        for (int r = 0; r < 4; ++r) {
            float* o0 = out + (T0 * 16 + 4 * g + r) * 64 + lr;
            float* o1 = out + ((T0 + 1) * 16 + 4 * g + r) * 64 + lr;
            #pragma unroll
            for (int j = 0; j < 4; ++j) {
                o0[16 * j] = r0[j][r];
                o1[16 * j] = r1[j][r];
            }
        }
    }
}

// ===================== FUSED fallback (r11, 93us proven) =====================

#define ISSUE_XV1(BUF, Q, XV) do {                                             \
    u16x8 id8 = *(const u16x8*)&idx_lds[BUF][Q][8 * g];                        \
    _Pragma("unroll")                                                          \
    for (int j = 0; j < 8; ++j) {                                              \
        if constexpr (XHALF) {                                                 \
            XV[j] = *(const half4_t*)(xh + (int)id8[j] * 64 + 4 * lr);         \
        } else {                                                               \
            f32x4 t4 = *(const f32x4*)(x + (int)id8[j] * 64 + 4 * lr);         \
            H4 hh;                                                             \
            hh.h2[0] = __builtin_amdgcn_cvt_pkrtz(t4.x, t4.y);                 \
            hh.h2[1] = __builtin_amdgcn_cvt_pkrtz(t4.z, t4.w);                 \
            XV[j] = hh.v;                                                      \
        }                                                                      \
    }                                                                          \
} while (0)

#define PACK_B(XV, BF) do {                                                    \
    _Pragma("unroll")                                                          \
    for (int nt = 0; nt < 4; ++nt) {                                           \
        half8 b;                                                               \
        _Pragma("unroll")                                                      \
        for (int j = 0; j < 8; ++j) b[j] = XV[j][nt];                          \
        BF[nt].v = b;                                                          \
    }                                                                          \
} while (0)

#define MFMA_DUMP(Q, CUR, BF) do {                                             \
    float w0v[8], w1v[8];                                                      \
    _Pragma("unroll")                                                          \
    for (int j = 0; j < 8; ++j) {                                              \
        f32x4 nb = nbr_lds[CUR][Q][8 * g + j];                                 \
        float dx = nb.x - kx0, dy = nb.y - ky0, dz = nb.z - kz0;               \
        w0v[j] = fmaxf(fmaf(__builtin_amdgcn_sqrtf(dx*dx + dy*dy + dz*dz), -INV_EXT, 1.f), 0.f); \
        float ex = nb.x - kx1, ey = nb.y - ky1, ez = nb.z - kz1;               \
        w1v[j] = fmaxf(fmaf(__builtin_amdgcn_sqrtf(ex*ex + ey*ey + ez*ez), -INV_EXT, cbias), 0.f); \
    }                                                                          \
    H8 A0, A1;                                                                 \
    _Pragma("unroll")                                                          \
    for (int p = 0; p < 4; ++p) {                                              \
        A0.h2[p] = __builtin_amdgcn_cvt_pkrtz(w0v[2*p], w0v[2*p+1]);           \
        A1.h2[p] = __builtin_amdgcn_cvt_pkrtz(w1v[2*p], w1v[2*p+1]);           \
    }                                                                          \
    char* gq = g_mem + (Q) * GPITCH;                                           \
    _Pragma("unroll")                                                          \
    for (int nt = 0; nt < 4; ++nt) {                                           \
        f32x4 z = {0.f, 0.f, 0.f, 0.f};                                        \
        f32x4 c0 = __builtin_amdgcn_mfma_f32_16x16x32_f16(A0.v, BF[nt].v, z, 0, 0, 0); \
        f32x4 c1 = __builtin_amdgcn_mfma_f32_16x16x32_f16(A1.v, BF[nt].v, z, 0, 0, 0); \
        const int ic = 16 * nt + lr;                                           \
        H4 h0;                                                                 \
        h0.h2[0] = __builtin_amdgcn_cvt_pkrtz(c0[0], c0[1]);                   \
        h0.h2[1] = __builtin_amdgcn_cvt_pkrtz(c0[2], c0[3]);                   \
        *(half4_t*)(gq + 2 * (ic * 28 + 4 * g)) = h0.v;                        \
        if (4 * g < 12) {                                                      \
            H4 h1;                                                             \
            h1.h2[0] = __builtin_amdgcn_cvt_pkrtz(c1[0], c1[1]);               \
            h1.h2[1] = __builtin_amdgcn_cvt_pkrtz(c1[2], c1[3]);               \
            *(half4_t*)(gq + 2 * (ic * 28 + 16 + 4 * g)) = h1.v;               \
        }                                                                      \
    }                                                                          \
} while (0)

#define BODY(T, TN, CUR, XV) do {                                              \
    half4_t xvB[8];                                                            \
    ISSUE_XV1(CUR, 2 * wid + 1, xvB);                                          \
    H8 BFA[4];                                                                 \
    PACK_B(XV, BFA);                                                           \
    const int nn   = (TN) * 16 + aq;                                           \
    const int idxN = inds[nn * 32 + ah];                                       \
    MFMA_DUMP(2 * wid, CUR, BFA);                                              \
    f32x4 vN;                                                                  \
    vN.x = s_pts[idxN * 3 + 0] - q_pts[nn * 3 + 0];                            \
    vN.y = s_pts[idxN * 3 + 1] - q_pts[nn * 3 + 1];                            \
    vN.z = s_pts[idxN * 3 + 2] - q_pts[nn * 3 + 2];                            \
    vN.w = 0.f;                                                                \
    H8 BFB[4];                                                                 \
    PACK_B(xvB, BFB);                                                          \
    MFMA_DUMP(2 * wid + 1, CUR, BFB);                                          \
    idx_lds[(CUR) ^ 1][aq][ah] = (unsigned short)idxN;                         \
    nbr_lds[(CUR) ^ 1][aq][ah] = vN;                                           \
    __syncthreads();                                                           \
    ISSUE_XV1((CUR) ^ 1, 2 * wid, XV);                                         \
    const half_t* wrow = WT + (16 * ot + lr) * 1792 + kh * 896 + 8 * g;        \
    const char*   gb   = g_mem + lr * GPITCH + kh * 1792;                      \
    f32x4 accA = {0.f, 0.f, 0.f, 0.f}, accB = {0.f, 0.f, 0.f, 0.f};            \
    _Pragma("unroll 7")                                                        \
    for (int s = 0; s < 28; s += 2) {                                          \
        half8 aA = *(const half8*)(gb + 64 * s + 16 * g);                      \
        half8 bA = *(const half8*)(wrow + 32 * s);                             \
        accA = __builtin_amdgcn_mfma_f32_16x16x32_f16(aA, bA, accA, 0, 0, 0);  \
        half8 aB = *(const half8*)(gb + 64 * (s + 1) + 16 * g);                \
        half8 bB = *(const half8*)(wrow + 32 * (s + 1));                       \
        accB = __builtin_amdgcn_mfma_f32_16x16x32_f16(aB, bB, accB, 0, 0, 0);  \
    }                                                                          \
    f32x4 acc = accA + accB;                                                   \
    if (kh) *(f32x4*)&red[ot][lane] = acc;                                     \
    __syncthreads();                                                           \
    if (!kh) {                                                                 \
        f32x4 p = red[ot][lane];                                               \
        const int o = 16 * ot + lr;                                            \
        _Pragma("unroll")                                                      \
        for (int r = 0; r < 4; ++r)                                            \
            out[((T) * 16 + 4 * g + r) * 64 + o] = acc[r] + p[r];              \
    }                                                                          \
} while (0)

template <int XHALF>
__global__ __launch_bounds__(512, 4) void kpconv_fused(
    const float* __restrict__ q_pts, const float* __restrict__ s_pts,
    const int*   __restrict__ inds,  const float* __restrict__ x,
    const half_t* __restrict__ xh,   const half_t* __restrict__ WT,
    float* __restrict__ out)
{
    __shared__ __align__(16) char   g_mem[16 * GPITCH];
    __shared__ __align__(16) unsigned short idx_lds[2][16][32];
    __shared__ __align__(16) f32x4  nbr_lds[2][16][32];
    __shared__ __align__(16) f32x4  red[4][64];

    const int tid  = threadIdx.x;
    const int lane = tid & 63, wid = tid >> 6;
    const int lr   = lane & 15, g = lane >> 4;
    const int aq   = tid >> 5,  ah = tid & 31;
    const int ot   = wid & 3,   kh = wid >> 2;

    const float kx0 = (float)((lr / 3) % 3 - 1) * KP_S;
    const float ky0 = (float)( lr / 9      - 1) * KP_S;
    const float kz0 = (float)( lr % 3      - 1) * KP_S;
    const int   l1  = lr + 16;
    const float kx1 = (float)((l1 / 3) % 3 - 1) * KP_S;
    const float ky1 = (float)( l1 / 9      - 1) * KP_S;
    const float kz1 = (float)( l1 % 3      - 1) * KP_S;
    const float cbias = (l1 < 27) ? 1.f : -1.f;

    {
        int n   = blockIdx.x * 16 + aq;
        int idx = inds[n * 32 + ah];
        idx_lds[0][aq][ah] = (unsigned short)idx;
        f32x4 v;
        v.x = s_pts[idx * 3 + 0] - q_pts[n * 3 + 0];
        v.y = s_pts[idx * 3 + 1] - q_pts[n * 3 + 1];
        v.z = s_pts[idx * 3 + 2] - q_pts[n * 3 + 2];
        v.w = 0.f;
        nbr_lds[0][aq][ah] = v;
    }
    __syncthreads();

    half4_t xv[8];
    ISSUE_XV1(0, 2 * wid, xv);

    int cur = 0;
    for (int t = blockIdx.x; t < NTILE; t += NBLK_F) {
        int tn = (t + NBLK_F < NTILE) ? t + NBLK_F : t;
        BODY(t, tn, cur, xv);
        cur ^= 1;
    }
}

// ================================ launcher ===================================

extern "C" void kernel_launch(void* const* d_in, const int* in_sizes, int n_in,
                              void* d_out, int out_size, void* d_ws, size_t ws_size,
                              hipStream_t stream) {
    const float* q_pts = (const float*)d_in[0];
    const float* s_pts = (const float*)d_in[1];
    const int*   inds  = (const int*)d_in[2];
    const float* x     = (const float*)d_in[3];
    const float* W     = (const float*)d_in[4];
    float* out = (float*)d_out;
    half_t* WT = (half_t*)d_ws;                               // 229376 B
    half_t* xh = (half_t*)((char*)d_ws + WT_BYTES);           // 5120000 B
    half_t* G  = (half_t*)((char*)d_ws + WT_BYTES + XH_BYTES);// 143360000 B

    const size_t need_split = (size_t)WT_BYTES + XH_BYTES + G_BYTES;
    const size_t need_xh    = (size_t)WT_BYTES + XH_BYTES;

    if (ws_size >= need_split) {
        build_wt_split<<<448, 256, 0, stream>>>(W, WT);
        build_xh<<<2500, 256, 0, stream>>>(x, xh);
        kpconvA<<<2500, 512, 0, stream>>>(q_pts, s_pts, inds, xh, G);
        kpconvB<<<1250, 256, 0, stream>>>(G, WT, out);
    } else if (ws_size >= need_xh) {
        build_wt_fused<<<448, 256, 0, stream>>>(W, WT);
        build_xh<<<2500, 256, 0, stream>>>(x, xh);
        kpconv_fused<1><<<NBLK_F, 512, 0, stream>>>(q_pts, s_pts, inds, x, xh, WT, out);
    } else {
        build_wt_fused<<<448, 256, 0, stream>>>(W, WT);
        kpconv_fused<0><<<NBLK_F, 512, 0, stream>>>(q_pts, s_pts, inds, x, xh, WT, out);
    }
}